// Round 11
// baseline (24.141 us; speedup 1.0000x reference)
//
#include <hip/hip_runtime.h>
#include <hip/hip_bf16.h>
#include <math.h>

// Problem constants (match reference)
#define V1N   225
#define V2N   224
#define RANK  64
#define ROWE  (RANK*32)   // 2048 elements per table row (4KB bf16)
#define PW    2           // producer waves per block (block = 2P + 2C)
#define NITER 4           // rounds; tokens per block = PW*NITER = 8

typedef __bf16  bf16x8 __attribute__((ext_vector_type(8)));
typedef float  f32x16 __attribute__((ext_vector_type(16)));
typedef float  f32x4  __attribute__((ext_vector_type(4)));
typedef int    i32x4  __attribute__((ext_vector_type(4)));

// ---------------------------------------------------------------------------
// Prep: dequantize int8 cores into bf16 tables in d_ws. One row per wave
// (113 blocks x 4 waves, fully parallel, ~1us). Dst layout per row:
// [s(4)][d(32)][rr(16)], r = s*16+rr -> each MFMA fragment load in tt_main
// is one contiguous 16B; a wave's fragment load covers a dense 1KB.
// core1 gets scale*(q-zp)*cos(phase[r]); core2 gets scale*(q-zp).
// ---------------------------------------------------------------------------
__global__ __launch_bounds__(256) void prep_tables(
    const int* __restrict__ c1q, const int* __restrict__ c2q,
    const float* __restrict__ s1p, const float* __restrict__ z1p,
    const float* __restrict__ s2p, const float* __restrict__ z2p,
    const float* __restrict__ phase,
    __bf16* __restrict__ t1, __bf16* __restrict__ t2)
{
    __shared__ float cosv[RANK];
    __shared__ float lds[4][64 * 33];   // per-wave slab, padded

    int t = threadIdx.x;
    if (t < RANK) cosv[t] = cosf(phase[t]);
    __syncthreads();

    int w    = t >> 6;
    int lane = t & 63;
    int v    = blockIdx.x * 4 + w;
    if (v >= V1N + V2N) return;

    bool is1 = (v < V1N);
    const int* src; __bf16* dst; float sc, zp;
    if (is1) { src = c1q + (size_t)v * ROWE;            dst = t1 + (size_t)v * ROWE;  sc = *s1p; zp = *z1p; }
    else     { int u = v - V1N; src = c2q + (size_t)u * ROWE; dst = t2 + (size_t)u * ROWE; sc = *s2p; zp = *z2p; }

    float* L = lds[w];
    #pragma unroll
    for (int p = 0; p < 4; ++p) {
        i32x4 q0 = reinterpret_cast<const i32x4*>(src)[p * 128 + lane * 2];
        i32x4 q1 = reinterpret_cast<const i32x4*>(src)[p * 128 + lane * 2 + 1];
        #pragma unroll
        for (int j = 0; j < 8; ++j) {
            int e = p * 512 + lane * 8 + j;   // src layout [r(64)][d(32)]
            int q = (j < 4) ? q0[j & 3] : q1[j & 3];
            float val = ((float)q - zp) * sc;
            if (is1) val *= cosv[e >> 5];
            L[(e >> 5) * 33 + (e & 31)] = val;
        }
    }
    // same-wave producer/consumer: per-wave in-order DS + lgkmcnt suffices
    #pragma unroll
    for (int h = 0; h < 4; ++h) {
        int d   = lane >> 1;
        int rr0 = (lane & 1) * 8;
        bf16x8 o8;
        #pragma unroll
        for (int j = 0; j < 8; ++j) {
            int r = h * 16 + rr0 + j;
            o8[j] = (__bf16)L[r * 33 + d];
        }
        *reinterpret_cast<bf16x8*>(dst + h * 512 + lane * 8) = o8;
    }
}

// ---------------------------------------------------------------------------
// Main: WAVE-SPECIALIZED producer/consumer pipeline.
// Evidence (R7 probe + R2..R9): main time = store-floor + front-end time,
// ADDITIVE -- in-wave load->store chains convoy and the read/write pipes
// never overlap. Fix: waves 0-1 are PRODUCERS (id -> fragment loads ->
// MFMA -> stage 32x32 tile in LDS), waves 2-3 are CONSUMERS (LDS read ->
// dense nt stores). Double-buffered slabs, one block barrier per round:
// the CU always has reads (producers) and writes (consumers) in flight.
//   round r: P writes tile[pw][r&1](tok r)  |  C stores tile[pw][(r-1)&1]
// Producer slack per round (~1.3us store-bound) >> its serial chain
// (~0.2us), so no register prefetch is needed -> low VGPR, launch_bounds
// (256,8) targets <=64 VGPR for 32 waves/CU.
// C/D layout (HW-verified): col=lane&31, row=(reg&3)+8*(reg>>2)+4*(lane>>5).
// Swapped operands (A=c2, B=c1) -> tile[d1][d2] with d2 quad-contiguous.
// ---------------------------------------------------------------------------
__global__ __launch_bounds__(256, 8) void tt_main(
    const int* __restrict__ ids,
    const __bf16* __restrict__ t1, const __bf16* __restrict__ t2,
    float* __restrict__ out, int n_tok)
{
    __shared__ float tile[PW][2][32 * 36];   // stride-36: b128-clean both sides

    int w    = threadIdx.x >> 6;      // 0..3
    int lane = threadIdx.x & 63;
    int m = lane & 31;                // d1
    int g = lane >> 5;
    bool producer = (w < PW);
    int pw = w & (PW - 1);
    int blk0 = blockIdx.x * (PW * NITER);

    int aoff[NITER], boff[NITER];
    if (producer) {
        #pragma unroll
        for (int r = 0; r < NITER; ++r) {
            int t = blk0 + r * PW + pw; if (t > n_tok - 1) t = n_tok - 1;
            unsigned id = (unsigned)ids[t];
            unsigned i1 = id / 224u; if (i1 > (unsigned)(V1N - 1)) i1 = V1N - 1;
            unsigned i2 = id % 224u;
            aoff[r] = (int)(i2 * ROWE);
            boff[r] = (int)(i1 * ROWE);
        }
    }
    const __bf16* abase = t2 + m * 16 + g * 8;   // A = c2
    const __bf16* bbase = t1 + m * 16 + g * 8;   // B = c1

    #pragma unroll
    for (int r = 0; r <= NITER; ++r) {
        if (producer) {
            if (r < NITER) {
                f32x16 acc;
                #pragma unroll
                for (int i = 0; i < 16; ++i) acc[i] = 0.0f;
                #pragma unroll
                for (int s = 0; s < 4; ++s) {
                    bf16x8 a = *reinterpret_cast<const bf16x8*>(abase + aoff[r] + s * 512);
                    bf16x8 b = *reinterpret_cast<const bf16x8*>(bbase + boff[r] + s * 512);
                    acc = __builtin_amdgcn_mfma_f32_32x32x16_bf16(a, b, acc, 0, 0, 0);
                }
                float* tp = tile[pw][r & 1];
                #pragma unroll
                for (int q = 0; q < 4; ++q) {
                    f32x4 v = { acc[4 * q + 0], acc[4 * q + 1], acc[4 * q + 2], acc[4 * q + 3] };
                    *reinterpret_cast<f32x4*>(tp + m * 36 + 8 * q + 4 * g) = v;
                }
            }
        } else {
            if (r >= 1) {
                int tok = blk0 + (r - 1) * PW + pw;
                const float* tp = tile[pw][(r - 1) & 1];
                if (tok < n_tok) {
                    float* o = out + (size_t)tok * 1024;
                    #pragma unroll
                    for (int p = 0; p < 4; ++p) {
                        int d1 = p * 8 + (lane >> 3);
                        int d2 = (lane & 7) * 4;
                        f32x4 v = *reinterpret_cast<const f32x4*>(tp + d1 * 36 + d2);
                        __builtin_nontemporal_store(v, reinterpret_cast<f32x4*>(o + p * 256 + lane * 4));
                    }
                }
            }
        }
        __syncthreads();   // single textual barrier, uniform trip count
    }
}

// ---------------------------------------------------------------------------
// Fallback (if d_ws is too small): fused on-the-fly dequant + MFMA.
// ---------------------------------------------------------------------------
__global__ __launch_bounds__(256) void tt_fused(
    const int* __restrict__ ids,
    const int* __restrict__ c1q, const int* __restrict__ c2q,
    const float* __restrict__ s1p, const float* __restrict__ z1p,
    const float* __restrict__ s2p, const float* __restrict__ z2p,
    const float* __restrict__ phase,
    float* __restrict__ out, int n_tok)
{
    __shared__ float cosv[RANK];
    if (threadIdx.x < RANK) cosv[threadIdx.x] = cosf(phase[threadIdx.x]);
    __syncthreads();

    int wave = (blockIdx.x << 2) + (threadIdx.x >> 6);
    if (wave >= n_tok) return;
    int lane = threadIdx.x & 63;
    int m = lane & 31;
    int g = lane >> 5;

    float s1 = *s1p, z1 = *z1p, s2 = *s2p, z2 = *z2p;

    unsigned id = (unsigned)ids[wave];
    unsigned i1 = id / 224u; if (i1 > (unsigned)(V1N - 1)) i1 = V1N - 1;
    unsigned i2 = id % 224u;

    const int* a_src = c2q + (size_t)i2 * ROWE + m;   // A = c2, [r][d] stride 32
    const int* b_src = c1q + (size_t)i1 * ROWE + m;   // B = c1

    f32x16 acc;
    #pragma unroll
    for (int i = 0; i < 16; ++i) acc[i] = 0.0f;

    #pragma unroll
    for (int s = 0; s < 4; ++s) {
        bf16x8 a, b;
        #pragma unroll
        for (int j = 0; j < 8; ++j) {
            int r = s * 16 + g * 8 + j;
            a[j] = (__bf16)((((float)a_src[r * 32]) - z2) * s2);
            b[j] = (__bf16)((((float)b_src[r * 32]) - z1) * s1 * cosv[r]);
        }
        acc = __builtin_amdgcn_mfma_f32_32x32x16_bf16(a, b, acc, 0, 0, 0);
    }

    float* o = out + (size_t)wave * 1024 + m * 32 + g * 4;
    #pragma unroll
    for (int q = 0; q < 4; ++q) {
        f32x4 v = { acc[4 * q + 0], acc[4 * q + 1], acc[4 * q + 2], acc[4 * q + 3] };
        __builtin_nontemporal_store(v, reinterpret_cast<f32x4*>(o + 8 * q));
    }
}

extern "C" void kernel_launch(void* const* d_in, const int* in_sizes, int n_in,
                              void* d_out, int out_size, void* d_ws, size_t ws_size,
                              hipStream_t stream) {
    const int*   ids = (const int*)d_in[0];
    const int*   c1q = (const int*)d_in[1];   // int8 values delivered as int32
    const float* s1  = (const float*)d_in[2];
    const float* z1  = (const float*)d_in[3];
    const int*   c2q = (const int*)d_in[4];
    const float* s2  = (const float*)d_in[5];
    const float* z2  = (const float*)d_in[6];
    const float* ph  = (const float*)d_in[7];
    float* out = (float*)d_out;

    int n_tok = in_sizes[0];                  // 16384
    int tpb   = PW * NITER;                   // 8 tokens per block
    int grid  = (n_tok + tpb - 1) / tpb;      // 2048 blocks

    size_t need = (size_t)(V1N + V2N) * ROWE * sizeof(__bf16);  // ~1.84 MB
    if (ws_size >= need) {
        __bf16* t1 = (__bf16*)d_ws;
        __bf16* t2 = t1 + (size_t)V1N * ROWE;
        prep_tables<<<(V1N + V2N + 3) / 4, 256, 0, stream>>>(c1q, c2q, s1, z1, s2, z2, ph, t1, t2);
        tt_main<<<grid, 256, 0, stream>>>(ids, t1, t2, out, n_tok);
    } else {
        int fgrid = (n_tok + 3) / 4;
        tt_fused<<<fgrid, 256, 0, stream>>>(ids, c1q, c2q, s1, z1, s2, z2, ph, out, n_tok);
    }
}